// Round 1
// baseline (450.269 us; speedup 1.0000x reference)
//
#include <hip/hip_runtime.h>
#include <stdint.h>

#define BB 16
#define NN 1024
#define DD 64
#define CC 64
#define KMAX 20

// ---------------- K0: counts + k_eff (one block) ----------------
__global__ void k0_counts(const void* __restrict__ maskp,
                          int* __restrict__ counts, int* __restrict__ keff) {
    __shared__ int scnt[BB];
    int tid = threadIdx.x;
    int w = tid >> 6, lane = tid & 63;   // wave w handles batch w
    const unsigned char* mb = (const unsigned char*)maskp;
    const int* mi = (const int*)maskp;
    // lengths[0] >= 256 so mask[0][1] is true. byte layout -> mb[1]!=0.
    // int32 (or f32) layout -> mb[1]==0, but mi[n]!=0 works for both.
    bool bytelayout = (mb[1] != 0);
    int s = 0;
    for (int i = 0; i < 16; ++i) {
        int n = lane + (i << 6);
        int v = bytelayout ? (mb[w * NN + n] ? 1 : 0) : (mi[w * NN + n] ? 1 : 0);
        s += v;
    }
    for (int off = 32; off; off >>= 1) s += __shfl_xor(s, off);
    if (lane == 0) scnt[w] = s;
    __syncthreads();
    if (tid < BB) {
        int minc = scnt[0];
        for (int q = 1; q < BB; ++q) minc = min(minc, scnt[q]);
        int kglob = min(KMAX, max(1, minc - 1));
        float c = (float)scnt[tid];
        float v = sqrtf(c / 50.0f) * 8.0f;           // match jnp f32 ops
        v = fminf(fmaxf(v, 8.0f), 20.0f);
        int kper = (int)v;                            // truncation like .astype(int32)
        counts[tid] = scnt[tid];
        keff[tid] = min(kper, kglob);
    }
}

// ---------------- K1: per-point feats: base = x@(W1a-W1b)+b1, fb = x@W1b, x2 ----------------
__global__ void k1_feats(const float* __restrict__ x, const float* __restrict__ W1,
                         const float* __restrict__ b1, float* __restrict__ base,
                         float* __restrict__ fb, float* __restrict__ x2) {
    int p = blockIdx.x * 4 + (threadIdx.x >> 6);
    int lane = threadIdx.x & 63;
    const float* xp = x + (size_t)p * DD;
    float xv = xp[lane];
    float sq = xv * xv;
    for (int off = 32; off; off >>= 1) sq += __shfl_xor(sq, off);
    if (lane == 0) x2[p] = sq;
    float acc_a = 0.f, acc_b = 0.f;
#pragma unroll
    for (int d = 0; d < DD; ++d) {
        float xd = xp[d];  // wave-uniform -> scalar load
        acc_a = fmaf(xd, W1[d * CC + lane], acc_a);
        acc_b = fmaf(xd, W1[(DD + d) * CC + lane], acc_b);
    }
    base[(size_t)p * CC + lane] = acc_a - acc_b + b1[lane];
    fb[(size_t)p * CC + lane] = acc_b;
}

// ---------------- K2: KNN top-20 per valid row (wave per row) ----------------
__global__ void k2_knn(const float* __restrict__ x, const float* __restrict__ x2,
                       const int* __restrict__ counts, const int* __restrict__ keff,
                       int* __restrict__ idx) {
    int p = blockIdx.x * 4 + (threadIdx.x >> 6);
    int lane = threadIdx.x & 63;
    int b = p >> 10, n = p & 1023;
    int cnt = counts[b];
    if (n >= cnt) return;  // out for this row is zero; idx never read
    int kef = keff[b];
    const float* xb = x + (((size_t)b) << 10) * DD;
    const float* xn = xb + (size_t)n * DD;
    float xr[DD];
#pragma unroll
    for (int t = 0; t < 16; ++t) {
        float4 v = ((const float4*)xn)[t];
        xr[4 * t + 0] = v.x; xr[4 * t + 1] = v.y;
        xr[4 * t + 2] = v.z; xr[4 * t + 3] = v.w;
    }
    float x2n = x2[(b << 10) + n];
    const float* x2b = x2 + (b << 10);
    unsigned long long packed[16];
#pragma unroll
    for (int t = 0; t < 16; ++t) {
        int m = (t << 6) + lane;
        unsigned long long pk = ~0ULL;
        if (m < cnt && m != n) {
            const float4* xm = (const float4*)(xb + (size_t)m * DD);
            float dot = 0.f;
#pragma unroll
            for (int u = 0; u < 16; ++u) {
                float4 c4 = xm[u];
                dot = fmaf(xr[4 * u + 0], c4.x, dot);
                dot = fmaf(xr[4 * u + 1], c4.y, dot);
                dot = fmaf(xr[4 * u + 2], c4.z, dot);
                dot = fmaf(xr[4 * u + 3], c4.w, dot);
            }
            float dd = (x2n + x2b[m]) - 2.0f * dot;   // same form as reference
            dd = fmaxf(dd, 0.0f);
            pk = ((unsigned long long)__float_as_uint(dd) << 32) | (unsigned)m;
        }
        packed[t] = pk;
    }
    // 20 rounds of global lexicographic min (dist, then lower index) == jax top_k order
    unsigned used = 0;
    int my_m = 0;
    for (int j = 0; j < KMAX; ++j) {
        unsigned long long best = ~0ULL;
        int bt = -1;
#pragma unroll
        for (int t = 0; t < 16; ++t) {
            bool ok = (!(used & (1u << t))) && (packed[t] < best);
            best = ok ? packed[t] : best;
            bt = ok ? t : bt;
        }
        unsigned long long g = best;
        for (int off = 32; off; off >>= 1) {
            unsigned long long o = __shfl_xor(g, off);
            g = (o < g) ? o : g;
        }
        if (best == g && bt >= 0) used |= (1u << bt);  // unique winner (m distinct)
        if (j == lane) my_m = (int)(unsigned)(g & 0xffffffffu);
    }
    if (lane < KMAX) {
        // pad slots [keff, 20) repeat first_valid == 0 (k_global == 20 since counts>=256)
        idx[(size_t)p * KMAX + lane] = (lane < kef) ? my_m : 0;
    }
}

// ---------------- K3: gather + GN + ReLU + W2 + maxpool ----------------
__global__ void k3_mlp(const float* __restrict__ base, const float* __restrict__ fb,
                       const int* __restrict__ idx, const int* __restrict__ counts,
                       const float* __restrict__ gamma, const float* __restrict__ beta,
                       const float* __restrict__ W2, const float* __restrict__ b2,
                       float* __restrict__ out) {
    __shared__ float sW2[CC * CC];
    __shared__ float sH[4][CC];
    for (int i = threadIdx.x; i < CC * CC; i += 256) sW2[i] = W2[i];
    int w = threadIdx.x >> 6, lane = threadIdx.x & 63;
    int p = blockIdx.x * 4 + w;
    int b = p >> 10, n = p & 1023;
    bool valid = n < counts[b];
    float basec = base[(size_t)p * CC + lane];
    float g = gamma[lane], be = beta[lane], b2c = b2[lane];
    const float* fbb = fb + ((((size_t)b) << 10)) * CC;
    float acc = -1e30f;
    __syncthreads();
    for (int j = 0; j < KMAX; ++j) {
        int m = valid ? idx[(size_t)p * KMAX + j] : 0;  // guard: idx poisoned for invalid rows
        float h = basec + fbb[(size_t)m * CC + lane];
        // GroupNorm, groups of 4 consecutive channels (16 groups)
        float s = h + __shfl_xor(h, 1);
        s += __shfl_xor(s, 2);
        float mu = s * 0.25f;
        float d = h - mu;
        float q = d * d;
        float qs = q + __shfl_xor(q, 1);
        qs += __shfl_xor(qs, 2);
        float var = qs * 0.25f;
        float hn = d * (1.0f / sqrtf(var + 1e-5f)) * g + be;
        hn = fmaxf(hn, 0.0f);  // ReLU
        sH[w][lane] = hn;
        __syncthreads();
        float a2 = b2c;
#pragma unroll
        for (int c2 = 0; c2 < CC; ++c2)
            a2 = fmaf(sH[w][c2], sW2[c2 * CC + lane], a2);
        acc = fmaxf(acc, a2);
        __syncthreads();
    }
    out[(size_t)p * CC + lane] = valid ? acc : 0.0f;
}

extern "C" void kernel_launch(void* const* d_in, const int* in_sizes, int n_in,
                              void* d_out, int out_size, void* d_ws, size_t ws_size,
                              hipStream_t stream) {
    const float* x     = (const float*)d_in[0];
    const void*  maskp = d_in[1];
    const float* W1    = (const float*)d_in[2];
    const float* b1    = (const float*)d_in[3];
    const float* gamma = (const float*)d_in[4];
    const float* beta  = (const float*)d_in[5];
    const float* W2    = (const float*)d_in[6];
    const float* b2    = (const float*)d_in[7];
    float* out = (float*)d_out;

    int* d_counts = (int*)d_ws;
    int* d_keff   = d_counts + 16;
    float* d_x2   = (float*)(d_counts + 32);
    float* d_base = d_x2 + BB * NN;
    float* d_fb   = d_base + (size_t)BB * NN * CC;
    int* d_idx    = (int*)(d_fb + (size_t)BB * NN * CC);

    hipLaunchKernelGGL(k0_counts, dim3(1), dim3(1024), 0, stream, maskp, d_counts, d_keff);
    hipLaunchKernelGGL(k1_feats, dim3(BB * NN / 4), dim3(256), 0, stream,
                       x, W1, b1, d_base, d_fb, d_x2);
    hipLaunchKernelGGL(k2_knn, dim3(BB * NN / 4), dim3(256), 0, stream,
                       x, d_x2, d_counts, d_keff, d_idx);
    hipLaunchKernelGGL(k3_mlp, dim3(BB * NN / 4), dim3(256), 0, stream,
                       d_base, d_fb, d_idx, d_counts, gamma, beta, W2, b2, out);
}

// Round 2
// 201.624 us; speedup vs baseline: 2.2332x; 2.2332x over previous
//
#include <hip/hip_runtime.h>
#include <stdint.h>

#define BB 16
#define NN 1024
#define DD 64
#define CC 64
#define KMAX 20
#define ROWS 8

// ---------------- K0: counts + k_eff (one block) ----------------
__global__ void k0_counts(const void* __restrict__ maskp,
                          int* __restrict__ counts, int* __restrict__ keff) {
    __shared__ int scnt[BB];
    int tid = threadIdx.x;
    int w = tid >> 6, lane = tid & 63;   // wave w handles batch w
    const unsigned char* mb = (const unsigned char*)maskp;
    const int* mi = (const int*)maskp;
    // lengths[0] >= 256 so mask[0][1] is true. byte layout -> mb[1]!=0.
    bool bytelayout = (mb[1] != 0);
    int s = 0;
    for (int i = 0; i < 16; ++i) {
        int n = lane + (i << 6);
        int v = bytelayout ? (mb[w * NN + n] ? 1 : 0) : (mi[w * NN + n] ? 1 : 0);
        s += v;
    }
    for (int off = 32; off; off >>= 1) s += __shfl_xor(s, off);
    if (lane == 0) scnt[w] = s;
    __syncthreads();
    if (tid < BB) {
        int minc = scnt[0];
        for (int q = 1; q < BB; ++q) minc = min(minc, scnt[q]);
        int kglob = min(KMAX, max(1, minc - 1));
        float c = (float)scnt[tid];
        float v = sqrtf(c / 50.0f) * 8.0f;
        v = fminf(fmaxf(v, 8.0f), 20.0f);
        int kper = (int)v;
        counts[tid] = scnt[tid];
        keff[tid] = min(kper, kglob);
    }
}

// ---------------- K1: base/fb feats + x2 + transpose x -> xT[b][d][n] ----------------
__global__ void k1_feats(const float* __restrict__ x, const float* __restrict__ W1,
                         const float* __restrict__ b1, float* __restrict__ base,
                         float* __restrict__ fb, float* __restrict__ x2,
                         float* __restrict__ xT) {
    __shared__ float sXT[DD][4];
    int w = threadIdx.x >> 6, lane = threadIdx.x & 63;
    int p = blockIdx.x * 4 + w;
    const float* xp = x + (size_t)p * DD;
    float xv = xp[lane];
    float sq = xv * xv;
    for (int off = 32; off; off >>= 1) sq += __shfl_xor(sq, off);
    if (lane == 0) x2[p] = sq;
    sXT[lane][w] = xv;
    float acc_a = 0.f, acc_b = 0.f;
#pragma unroll
    for (int d = 0; d < DD; ++d) {
        float xd = __shfl(xv, d);  // == xp[d], bit-identical
        acc_a = fmaf(xd, W1[d * CC + lane], acc_a);
        acc_b = fmaf(xd, W1[(DD + d) * CC + lane], acc_b);
    }
    base[(size_t)p * CC + lane] = acc_a - acc_b + b1[lane];
    fb[(size_t)p * CC + lane] = acc_b;
    __syncthreads();
    int t = threadIdx.x;
    int d = t >> 2, po = t & 3;
    int p0 = blockIdx.x * 4;
    int b = p0 >> 10, nb = p0 & 1023;
    xT[(((size_t)(b << 6) + d) << 10) + nb + po] = sXT[d][po];
}

// ---------------- K2: GEMM-style dist + fused top-k (coalesced) ----------------
__global__ __launch_bounds__(256) void k2_knn(const float* __restrict__ x,
                                              const float* __restrict__ xT,
                                              const float* __restrict__ x2,
                                              const int* __restrict__ counts,
                                              const int* __restrict__ keff,
                                              int* __restrict__ idx) {
    __shared__ float sD[ROWS][NN];    // raw dot products
    __shared__ float sRow[ROWS][DD];
    __shared__ float sX2[NN];
    int b = blockIdx.x >> 7;
    int n0 = (blockIdx.x & 127) * ROWS;
    int w = threadIdx.x >> 6, lane = threadIdx.x & 63;
    int cnt = counts[b], kef = keff[b];
    int t = threadIdx.x;
    if (t < ROWS * 16) {
        int r = t >> 4, dc = (t & 15) << 2;
        *(float4*)&sRow[r][dc] =
            *(const float4*)(x + ((size_t)(b << 10) + n0 + r) * DD + dc);
    }
    *(float4*)&sX2[t << 2] = *(const float4*)(x2 + (b << 10) + (t << 2));
    __syncthreads();

    // GEMM phase: wave w covers candidates c0 = w*256 + lane*4 .. +3, all 8 rows
    float4 acc[ROWS];
#pragma unroll
    for (int r = 0; r < ROWS; ++r) acc[r] = make_float4(0.f, 0.f, 0.f, 0.f);
    const float* xTb = xT + ((size_t)b << 16);
    int c0 = (w << 8) + (lane << 2);
    for (int d0 = 0; d0 < DD; d0 += 4) {
        float4 cv0 = *(const float4*)(xTb + ((size_t)(d0 + 0) << 10) + c0);
        float4 cv1 = *(const float4*)(xTb + ((size_t)(d0 + 1) << 10) + c0);
        float4 cv2 = *(const float4*)(xTb + ((size_t)(d0 + 2) << 10) + c0);
        float4 cv3 = *(const float4*)(xTb + ((size_t)(d0 + 3) << 10) + c0);
#pragma unroll
        for (int r = 0; r < ROWS; ++r) {
            float4 rv = *(const float4*)(&sRow[r][d0]);   // wave-uniform broadcast
            // d-order ascending per output -> bit-identical to R1's dot
            acc[r].x = fmaf(rv.x, cv0.x, acc[r].x);
            acc[r].y = fmaf(rv.x, cv0.y, acc[r].y);
            acc[r].z = fmaf(rv.x, cv0.z, acc[r].z);
            acc[r].w = fmaf(rv.x, cv0.w, acc[r].w);
            acc[r].x = fmaf(rv.y, cv1.x, acc[r].x);
            acc[r].y = fmaf(rv.y, cv1.y, acc[r].y);
            acc[r].z = fmaf(rv.y, cv1.z, acc[r].z);
            acc[r].w = fmaf(rv.y, cv1.w, acc[r].w);
            acc[r].x = fmaf(rv.z, cv2.x, acc[r].x);
            acc[r].y = fmaf(rv.z, cv2.y, acc[r].y);
            acc[r].z = fmaf(rv.z, cv2.z, acc[r].z);
            acc[r].w = fmaf(rv.z, cv2.w, acc[r].w);
            acc[r].x = fmaf(rv.w, cv3.x, acc[r].x);
            acc[r].y = fmaf(rv.w, cv3.y, acc[r].y);
            acc[r].z = fmaf(rv.w, cv3.z, acc[r].z);
            acc[r].w = fmaf(rv.w, cv3.w, acc[r].w);
        }
    }
#pragma unroll
    for (int r = 0; r < ROWS; ++r) *(float4*)&sD[r][c0] = acc[r];
    __syncthreads();

    // selection phase: wave w handles rows w and w+4
    for (int rr = 0; rr < 2; ++rr) {
        int r = w + rr * 4;
        int n = n0 + r;
        if (n >= cnt) continue;                     // wave-uniform
        float x2n = sX2[n];
        unsigned long long packed[16];
#pragma unroll
        for (int tt = 0; tt < 16; ++tt) {
            int c = (tt << 6) + lane;
            float dot = sD[r][c];
            float dd = fmaxf((x2n + sX2[c]) - 2.0f * dot, 0.0f);
            packed[tt] = (c < cnt && c != n)
                ? (((unsigned long long)__float_as_uint(dd) << 32) | (unsigned)c)
                : ~0ULL;
        }
        unsigned used = 0;
        int my_m = 0;
        for (int j = 0; j < kef; ++j) {
            unsigned long long best = ~0ULL;
            int bt = -1;
#pragma unroll
            for (int tt = 0; tt < 16; ++tt) {
                bool ok = (!(used & (1u << tt))) && (packed[tt] < best);
                best = ok ? packed[tt] : best;
                bt = ok ? tt : bt;
            }
            unsigned long long g = best;
            for (int off = 32; off; off >>= 1) {
                unsigned long long o = __shfl_xor(g, off);
                g = (o < g) ? o : g;
            }
            if (best == g && bt >= 0) used |= (1u << bt);
            if (j == lane) my_m = (int)(unsigned)(g & 0xffffffffu);
        }
        if (lane < KMAX) {
            size_t p = (size_t)(b << 10) + n;
            idx[p * KMAX + lane] = (lane < kef) ? my_m : 0;
        }
    }
}

// ---------------- K3: gather + GN + ReLU + W2 + maxpool (barrier-free) ----------------
__global__ __launch_bounds__(256) void k3_mlp(const float* __restrict__ base,
                                              const float* __restrict__ fb,
                                              const int* __restrict__ idx,
                                              const int* __restrict__ counts,
                                              const float* __restrict__ gamma,
                                              const float* __restrict__ beta,
                                              const float* __restrict__ W2,
                                              const float* __restrict__ b2,
                                              float* __restrict__ out) {
    __shared__ float sH[4][CC];
    int w = threadIdx.x >> 6, lane = threadIdx.x & 63;
    int p = blockIdx.x * 4 + w;
    int b = p >> 10, n = p & 1023;
    bool valid = n < counts[b];                     // wave-uniform
    if (!valid) { out[(size_t)p * CC + lane] = 0.0f; return; }
    float w2c[CC];                                  // W2 column `lane` in VGPRs
#pragma unroll
    for (int c = 0; c < CC; ++c) w2c[c] = W2[(c << 6) + lane];
    float basec = base[(size_t)p * CC + lane];
    float g = gamma[lane], be = beta[lane], b2c = b2[lane];
    const float* fbb = fb + ((size_t)(b << 10)) * CC;
    const int* idxp = idx + (size_t)p * KMAX;
    float acc = -1e30f;
    for (int j = 0; j < KMAX; ++j) {
        int m = idxp[j];                            // wave-uniform
        float h = basec + fbb[((size_t)m << 6) + lane];  // coalesced 256B
        float s = h + __shfl_xor(h, 1);
        s += __shfl_xor(s, 2);
        float mu = s * 0.25f;
        float d = h - mu;
        float q = d * d;
        float qs = q + __shfl_xor(q, 1);
        qs += __shfl_xor(qs, 2);
        float var = qs * 0.25f;
        float hn = d * (1.0f / sqrtf(var + 1e-5f)) * g + be;
        hn = fmaxf(hn, 0.0f);
        sH[w][lane] = hn;
        __builtin_amdgcn_sched_barrier(0);
        asm volatile("s_waitcnt lgkmcnt(0)" ::: "memory");
        __builtin_amdgcn_sched_barrier(0);
        float a2 = b2c;
        const float4* sh4 = (const float4*)(&sH[w][0]);
#pragma unroll
        for (int qq = 0; qq < 16; ++qq) {
            float4 hv = sh4[qq];                    // wave-uniform broadcast b128
            a2 = fmaf(hv.x, w2c[4 * qq + 0], a2);
            a2 = fmaf(hv.y, w2c[4 * qq + 1], a2);
            a2 = fmaf(hv.z, w2c[4 * qq + 2], a2);
            a2 = fmaf(hv.w, w2c[4 * qq + 3], a2);
        }
        acc = fmaxf(acc, a2);
        __builtin_amdgcn_sched_barrier(0);
    }
    out[(size_t)p * CC + lane] = acc;
}

extern "C" void kernel_launch(void* const* d_in, const int* in_sizes, int n_in,
                              void* d_out, int out_size, void* d_ws, size_t ws_size,
                              hipStream_t stream) {
    const float* x     = (const float*)d_in[0];
    const void*  maskp = d_in[1];
    const float* W1    = (const float*)d_in[2];
    const float* b1    = (const float*)d_in[3];
    const float* gamma = (const float*)d_in[4];
    const float* beta  = (const float*)d_in[5];
    const float* W2    = (const float*)d_in[6];
    const float* b2    = (const float*)d_in[7];
    float* out = (float*)d_out;

    int* d_counts = (int*)d_ws;
    int* d_keff   = d_counts + 16;
    float* d_x2   = (float*)(d_counts + 32);
    float* d_base = d_x2 + BB * NN;
    float* d_fb   = d_base + (size_t)BB * NN * CC;
    int* d_idx    = (int*)(d_fb + (size_t)BB * NN * CC);
    // xT[b][d][n] lives in d_out: free until k3, exactly B*N*C floats
    float* d_xT   = (float*)d_out;

    hipLaunchKernelGGL(k0_counts, dim3(1), dim3(1024), 0, stream, maskp, d_counts, d_keff);
    hipLaunchKernelGGL(k1_feats, dim3(BB * NN / 4), dim3(256), 0, stream,
                       x, W1, b1, d_base, d_fb, d_x2, d_xT);
    hipLaunchKernelGGL(k2_knn, dim3(BB * (NN / ROWS)), dim3(256), 0, stream,
                       x, d_xT, d_x2, d_counts, d_keff, d_idx);
    hipLaunchKernelGGL(k3_mlp, dim3(BB * NN / 4), dim3(256), 0, stream,
                       d_base, d_fb, d_idx, d_counts, gamma, beta, W2, b2, out);
}